// Round 17
// baseline (165.536 us; speedup 1.0000x reference)
//
#include <hip/hip_runtime.h>

typedef unsigned short u16;
typedef short bf16x8 __attribute__((ext_vector_type(8)));
typedef float f32x4 __attribute__((ext_vector_type(4)));
typedef unsigned short u16x8 __attribute__((ext_vector_type(8)));
typedef unsigned short u16x4 __attribute__((ext_vector_type(4)));

union bfr { unsigned int u[4]; bf16x8 v; };

__device__ __forceinline__ u16 f2bf(float f) {
    unsigned int u = __builtin_bit_cast(unsigned int, f);
    u = (u + 0x7fffu + ((u >> 16) & 1u)) >> 16;
    return (u16)u;
}

// v_cvt_pk_bf16_f32: dst = [bf16(hi) : bf16(lo)] (RNE)
__device__ __forceinline__ unsigned int cvtpk(float lo, float hi) {
    unsigned int r;
    asm("v_cvt_pk_bf16_f32 %0, %1, %2" : "=v"(r) : "v"(lo), "v"(hi));
    return r;
}

// async 16B global -> LDS (dest = wave-uniform base + lane*16)
__device__ __forceinline__ void gload16(const u16* src, u16* lds_dst) {
    __builtin_amdgcn_global_load_lds(
        (const __attribute__((address_space(1))) unsigned int*)src,
        (__attribute__((address_space(3))) unsigned int*)lds_dst, 16, 0, 0);
}

// ---------------------------------------------------------------- prep: per-wave LN + tiled transpose (r15)
__global__ __launch_bounds__(256) void prep_ln_k(
    const float* __restrict__ x, const float* __restrict__ ctx,
    const float* __restrict__ g1, const float* __restrict__ b1,
    const float* __restrict__ g2, const float* __restrict__ b2,
    const float* __restrict__ Wq, const float* __restrict__ Wkv,
    const float* __restrict__ Wp,
    u16* __restrict__ xn, u16* __restrict__ cn,
    u16* __restrict__ WqT, u16* __restrict__ WkvT, u16* __restrict__ WpT)
{
    const int id = blockIdx.x;
    const int t = threadIdx.x;
    if (id >= 4096) {
        __shared__ float T[64][65];
        int t2 = id - 4096;
        const float* src; u16* dst; int lds, k0, n0;
        if (t2 < 288) { src = Wkv; dst = WkvT; lds = 1536; k0 = (t2 / 24) * 64; n0 = (t2 % 24) * 64; }
        else if (t2 < 432) { int u = t2 - 288; src = Wq; dst = WqT; lds = 768; k0 = (u / 12) * 64; n0 = (u % 12) * 64; }
        else { int u = t2 - 432; src = Wp; dst = WpT; lds = 768; k0 = (u / 12) * 64; n0 = (u % 12) * 64; }
        const int rr = t >> 4, c4 = (t & 15) * 4;
        #pragma unroll
        for (int it = 0; it < 4; it++) {
            int r = rr + it * 16;
            f32x4 v = *(const f32x4*)&src[(long)(k0 + r) * lds + n0 + c4];
            #pragma unroll
            for (int j = 0; j < 4; j++) T[c4 + j][r] = v[j];
        }
        __syncthreads();
        #pragma unroll
        for (int it = 0; it < 4; it++) {
            int r = rr + it * 16;
            u16x4 w;
            #pragma unroll
            for (int j = 0; j < 4; j++) w[j] = f2bf(T[r][c4 + j]);
            *(u16x4*)&dst[(long)(n0 + r) * 768 + k0 + c4] = w;
        }
        return;
    }
    const int lane = t & 63, w = t >> 6;
    const int row = id * 4 + w;
    const float* src; const float* g; const float* b; u16* dst;
    if (row < 8192) { src = x + (long)row * 768; g = g1; b = b1; dst = xn + (long)row * 768; }
    else { int r = row - 8192; src = ctx + (long)r * 768; g = g2; b = b2; dst = cn + (long)r * 768; }

    const int c0 = lane * 4;
    f32x4 v0 = *(const f32x4*)&src[c0];
    f32x4 v1 = *(const f32x4*)&src[c0 + 256];
    f32x4 v2 = *(const f32x4*)&src[c0 + 512];
    float s = (v0[0] + v0[1] + v0[2] + v0[3]) + (v1[0] + v1[1] + v1[2] + v1[3])
            + (v2[0] + v2[1] + v2[2] + v2[3]);
    #pragma unroll
    for (int o = 32; o; o >>= 1) s += __shfl_xor(s, o);
    const float mu = s * (1.0f / 768.0f);
    float q = 0.f;
    #pragma unroll
    for (int j = 0; j < 4; j++) { float d = v0[j] - mu; q += d * d; }
    #pragma unroll
    for (int j = 0; j < 4; j++) { float d = v1[j] - mu; q += d * d; }
    #pragma unroll
    for (int j = 0; j < 4; j++) { float d = v2[j] - mu; q += d * d; }
    #pragma unroll
    for (int o = 32; o; o >>= 1) q += __shfl_xor(q, o);
    const float rs = rsqrtf(q * (1.0f / 768.0f) + 1e-5f);

    f32x4 ga0 = *(const f32x4*)&g[c0],       ba0 = *(const f32x4*)&b[c0];
    f32x4 ga1 = *(const f32x4*)&g[c0 + 256], ba1 = *(const f32x4*)&b[c0 + 256];
    f32x4 ga2 = *(const f32x4*)&g[c0 + 512], ba2 = *(const f32x4*)&b[c0 + 512];
    u16x4 w0, w1, w2;
    #pragma unroll
    for (int j = 0; j < 4; j++) {
        w0[j] = f2bf((v0[j] - mu) * rs * ga0[j] + ba0[j]);
        w1[j] = f2bf((v1[j] - mu) * rs * ga1[j] + ba1[j]);
        w2[j] = f2bf((v2[j] - mu) * rs * ga2[j] + ba2[j]);
    }
    *(u16x4*)&dst[c0]       = w0;
    *(u16x4*)&dst[c0 + 256] = w1;
    *(u16x4*)&dst[c0 + 512] = w2;
}

// ---------------------------------------------------------------- fused Q + KV projection
// WAVE-PRIVATE BARRIER-FREE form: each wave owns a 64x64 output tile and a
// private 16 KB LDS slice (2 buffers x (A 4KB | B 4KB)). NO __syncthreads in
// the K-loop — per-wave pipeline: issue stage(t+1) -> s_waitcnt vmcnt(8)
// (tile t landed, t+1's 8 loads stay in flight) -> ds_read -> 16 MFMA.
// Waves slide freely (no convoy). Zero-conflict (r>>1)&3 involution.
__global__ __launch_bounds__(256) void qkv_k(
    const u16* __restrict__ xn, const u16* __restrict__ cn,
    const u16* __restrict__ WqT, const u16* __restrict__ WkvT,
    const float* __restrict__ bq, const float* __restrict__ bkv,
    u16* __restrict__ Qb, u16* __restrict__ Kb, u16* __restrict__ Vt)
{
    __shared__ u16 L[4][2][4096];   // [wave][buf][A:0..2047 | B:2048..4095], 64 KB
    const int id = blockIdx.x;
    const int swz = (id & 7) * 144 + (id >> 3);   // XCD-chunked over 1152
    const int tid = threadIdx.x, lane = tid & 63, wid = tid >> 6;
    const int g = lane >> 4, i15 = lane & 15;

    // wave-tile decode: 4608 tiles = 128 row-tiles x 36 col-tiles (12 Q + 24 KV)
    const int wt = swz * 4 + wid;
    const int rt = wt / 36, c36 = wt % 36;
    const bool isQ = c36 < 12;
    const u16* A  = isQ ? xn : cn;
    const u16* Bt = isQ ? WqT : WkvT;
    const float* bias = isQ ? bq : bkv;
    const int row0 = rt * 64;
    const int col0 = (isQ ? c36 : (c36 - 12)) * 64;

    // staging sources: 256 chunks of 16B per operand tile (64 rows x 64B), 4/lane
    const u16* srcA[4]; const u16* srcB[4];
    #pragma unroll
    for (int c = 0; c < 4; c++) {
        int ch = c * 64 + lane;
        int r = ch >> 2, sl = ch & 3;
        int colx = ((sl ^ ((r >> 1) & 3)) << 3);   // pre-swizzled source col
        srcA[c] = A  + (long)(row0 + r) * 768 + colx;
        srcB[c] = Bt + (long)(col0 + r) * 768 + colx;
    }

    // twisted fragment read offsets (u16 units within a 4KB operand slice)
    int foff[4];
    #pragma unroll
    for (int m = 0; m < 4; m++) {
        int R = m * 16 + i15;
        foff[m] = R * 32 + ((g ^ ((R >> 1) & 3)) << 3);
    }

    f32x4 acc[4][4] = {};

#define WSTAGE(BUF, T) do {                                              \
    _Pragma("unroll")                                                    \
    for (int c_ = 0; c_ < 4; c_++)                                       \
        gload16(srcA[c_] + (T) * 32, &L[wid][BUF][c_ * 512]);            \
    _Pragma("unroll")                                                    \
    for (int c_ = 0; c_ < 4; c_++)                                       \
        gload16(srcB[c_] + (T) * 32, &L[wid][BUF][2048 + c_ * 512]);     \
} while (0)

    WSTAGE(0, 0);
    #pragma unroll
    for (int t = 0; t < 24; t++) {
        if (t + 1 < 24) {
            WSTAGE((t + 1) & 1, t + 1);
            asm volatile("s_waitcnt vmcnt(8)" ::: "memory");   // tile t landed
        } else {
            asm volatile("s_waitcnt vmcnt(0)" ::: "memory");
        }
        __builtin_amdgcn_sched_barrier(0);
        const u16* Lb = &L[wid][t & 1][0];
        bf16x8 av[4], bv[4];
        #pragma unroll
        for (int m = 0; m < 4; m++) av[m] = *(const bf16x8*)&Lb[foff[m]];
        #pragma unroll
        for (int n = 0; n < 4; n++) bv[n] = *(const bf16x8*)&Lb[2048 + foff[n]];
        #pragma unroll
        for (int m = 0; m < 4; m++)
            #pragma unroll
            for (int n = 0; n < 4; n++)
                acc[m][n] = __builtin_amdgcn_mfma_f32_16x16x32_bf16(av[m], bv[n], acc[m][n], 0, 0, 0);
    }
#undef WSTAGE

    float bv4[4];
    #pragma unroll
    for (int n = 0; n < 4; n++) bv4[n] = bias[col0 + n * 16 + i15];

    #pragma unroll
    for (int m = 0; m < 4; m++) {
        #pragma unroll
        for (int n = 0; n < 4; n++) {
            const int col = col0 + n * 16 + i15;
            #pragma unroll
            for (int r = 0; r < 4; r++) {
                const int row = row0 + m * 16 + g * 4 + r;
                float v = acc[m][n][r];
                if (isQ) {
                    v = (v + bv4[n]) * 0.14724444706f;   // 96^-0.5 * log2(e)
                    int b = row >> 10, l = row & 1023;
                    int h = col / 96, d = col % 96;
                    Qb[((long)(b * 8 + h) * 1024 + l) * 96 + d] = f2bf(v);
                } else {
                    v += bv4[n];
                    int b = row >> 10, mt = row & 1023;
                    if (col < 768) {
                        int h = col / 96, d = col % 96;
                        Kb[((long)(b * 8 + h) * 1024 + mt) * 96 + d] = f2bf(v);
                    } else {
                        int cc = col - 768;
                        int h = cc / 96, d = cc % 96;
                        Vt[((long)(b * 8 + h) * 96 + d) * 1024 + mt] = f2bf(v);
                    }
                }
            }
        }
    }
}

// ---------------------------------------------------------------- fused flash attention (r15, unchanged)
__global__ __launch_bounds__(256) void flash_k(
    const u16* __restrict__ Qb, const u16* __restrict__ Kb,
    const u16* __restrict__ Vt, u16* __restrict__ Ob)
{
    const int i = blockIdx.x;
    const int s8 = i >> 3;
    const int bh = (i & 7) * 8 + (s8 >> 4);   // XCD-grouped: 8 bh per XCD
    const int qt = s8 & 15;
    const int tid = threadIdx.x, lane = tid & 63, wid = tid >> 6;
    const int g = lane >> 4, i15 = lane & 15;

    __shared__ u16 Ks[6144];      // single buffer, 12 KB, twisted slots
    __shared__ u16 Vs[2][6144];   // [96][64] swizzled, 2 x 12 KB

    const long baseQK = (long)bh * 98304;
    const u16* Kt  = Kb + baseQK;
    const u16* Vtp = Vt + baseQK;

    bf16x8 qf[3];
    {
        const u16* qrow = Qb + baseQK + (long)(qt * 64 + wid * 16 + i15) * 96 + g * 8;
        qf[0] = *(const bf16x8*)(qrow);
        qf[1] = *(const bf16x8*)(qrow + 32);
        qf[2] = *(const bf16x8*)(qrow + 64);
    }

    int krd[4][3];
    #pragma unroll
    for (int n = 0; n < 4; n++) {
        int q4 = i15 >> 2, rr = i15 & 3, m = n >> 1;
        int R = (n & 1) ? (m * 32 + ((q4 ^ 2) << 3) + 4 + rr)
                        : (m * 32 + (q4 << 3) + rr);
        #pragma unroll
        for (int kd = 0; kd < 3; kd++)
            krd[n][kd] = kd * 2048 + R * 32 + ((g ^ ((R >> 3) & 3) ^ kd) << 3);
    }
    int vrd[6][2];
    #pragma unroll
    for (int n6 = 0; n6 < 6; n6++) {
        int row = n6 * 16 + i15;
        #pragma unroll
        for (int kk = 0; kk < 2; kk++)
            vrd[n6][kk] = row * 64 + ((kk * 32 + g * 8) ^ ((row & 7) << 3));
    }

    int kgo[3], kwr[3], vgo[3], vwr[3];
    #pragma unroll
    for (int it = 0; it < 3; it++) {
        int e = tid + it * 256;
        int r = e / 12, cEl = (e % 12) * 8;
        int kd = cEl >> 5, slot = (cEl >> 3) & 3;
        kgo[it] = r * 96 + cEl;
        kwr[it] = kd * 2048 + r * 32 + ((slot ^ ((r >> 3) & 3) ^ kd) << 3);
        int d = e >> 3, m8 = (e & 7) * 8;
        vgo[it] = d * 1024 + m8;
        vwr[it] = d * 64 + (m8 ^ ((d & 7) << 3));
    }

    u16x8 kreg[3], vreg[3];
    #pragma unroll
    for (int it = 0; it < 3; it++) {
        kreg[it] = *(const u16x8*)&Kt[kgo[it]];
        vreg[it] = *(const u16x8*)&Vtp[vgo[it]];
    }
    #pragma unroll
    for (int it = 0; it < 3; it++) {
        *(u16x8*)&Ks[kwr[it]] = kreg[it];
        *(u16x8*)&Vs[0][vwr[it]] = vreg[it];
    }

    f32x4 o[6] = {};
    float lsum = 0.f;
    int cur = 0;

    for (int t = 0; t < 16; t++) {
        __syncthreads();
        if (t < 15) {
            #pragma unroll
            for (int it = 0; it < 3; it++) {
                kreg[it] = *(const u16x8*)&Kt[(t + 1) * 6144 + kgo[it]];
                vreg[it] = *(const u16x8*)&Vtp[(t + 1) * 64 + vgo[it]];
            }
        }

        f32x4 s[4] = {};
        #pragma unroll
        for (int kd = 0; kd < 3; kd++) {
            #pragma unroll
            for (int n = 0; n < 4; n++) {
                bf16x8 kf = *(const bf16x8*)&Ks[krd[n][kd]];
                s[n] = __builtin_amdgcn_mfma_f32_16x16x32_bf16(kf, qf[kd], s[n], 0, 0, 0);
            }
        }
        __syncthreads();
        if (t < 15) {
            #pragma unroll
            for (int it = 0; it < 3; it++)
                *(u16x8*)&Ks[kwr[it]] = kreg[it];
        }

        unsigned int pk[4][2];
        #pragma unroll
        for (int n = 0; n < 4; n++) {
            float p0 = exp2f(s[n][0]), p1 = exp2f(s[n][1]);
            float p2 = exp2f(s[n][2]), p3 = exp2f(s[n][3]);
            lsum += (p0 + p1) + (p2 + p3);
            pk[n][0] = cvtpk(p0, p1);
            pk[n][1] = cvtpk(p2, p3);
        }

        #pragma unroll
        for (int kk = 0; kk < 2; kk++) {
            bfr pa;
            pa.u[0] = pk[kk * 2][0];
            pa.u[1] = pk[kk * 2][1];
            pa.u[2] = __shfl_xor(pk[kk * 2 + 1][0], 32);
            pa.u[3] = __shfl_xor(pk[kk * 2 + 1][1], 32);
            #pragma unroll
            for (int n6 = 0; n6 < 6; n6++) {
                bf16x8 vf = *(const bf16x8*)&Vs[cur][vrd[n6][kk]];
                o[n6] = __builtin_amdgcn_mfma_f32_16x16x32_bf16(pa.v, vf, o[n6], 0, 0, 0);
            }
        }

        if (t < 15) {
            #pragma unroll
            for (int it = 0; it < 3; it++)
                *(u16x8*)&Vs[cur ^ 1][vwr[it]] = vreg[it];
        }
        cur ^= 1;
    }

    lsum += __shfl_xor(lsum, 16);
    lsum += __shfl_xor(lsum, 32);
    float linv = 1.0f / lsum;

    const int b = bh >> 3, h = bh & 7;
    #pragma unroll
    for (int r = 0; r < 4; r++) {
        float lr = __shfl(linv, g * 4 + r);
        int row = qt * 64 + wid * 16 + g * 4 + r;
        long base = ((long)(b * 1024 + row)) * 768 + h * 96;
        #pragma unroll
        for (int n6 = 0; n6 < 6; n6++)
            Ob[base + n6 * 16 + i15] = f2bf(o[n6][r] * lr);
    }
}

// ---------------------------------------------------------------- out projection (64x128 tiles, r16) + attn_map
__global__ __launch_bounds__(256) void out_k(
    const u16* __restrict__ Ob, const u16* __restrict__ WpT,
    const float* __restrict__ bp, const float* __restrict__ resid,
    float* __restrict__ out, float* __restrict__ amap)
{
    const int id = blockIdx.x;
    if (id >= 768) {
        amap[(id - 768) * 256 + threadIdx.x] = 1.0f;
        return;
    }
    __shared__ u16 As[64 * 32];
    __shared__ u16 Bs[128 * 32];
    const int swz = (id & 7) * 96 + (id >> 3);   // XCD-chunked over 768
    const int rt = swz / 6, ct = swz % 6;
    const int row0 = rt * 64, col0 = ct * 128;
    const int tid = threadIdx.x, lane = tid & 63, wid = tid >> 6;
    const int wr = wid >> 1, wc = wid & 1;
    const int g = lane >> 4, i15 = lane & 15;

    const u16* srcA; const u16* srcB[2];
    {
        int r = tid >> 2, sl = tid & 3;
        srcA = Ob + (long)(row0 + r) * 768 + ((sl ^ ((r >> 1) & 3)) << 3);
        #pragma unroll
        for (int c = 0; c < 2; c++) {
            int ch = c * 256 + tid;
            int rb = ch >> 2, slb = ch & 3;
            srcB[c] = WpT + (long)(col0 + rb) * 768 + ((slb ^ ((rb >> 1) & 3)) << 3);
        }
    }
    const int dA = wid * 512;
    int dB[2]; dB[0] = wid * 512; dB[1] = 2048 + wid * 512;

    int aoff[2], boff[4];
    #pragma unroll
    for (int m = 0; m < 2; m++) {
        int R = wr * 32 + m * 16 + i15;
        aoff[m] = R * 32 + ((g ^ ((R >> 1) & 3)) << 3);
    }
    #pragma unroll
    for (int n = 0; n < 4; n++) {
        int R = wc * 64 + n * 16 + i15;
        boff[n] = R * 32 + ((g ^ ((R >> 1) & 3)) << 3);
    }

    f32x4 acc[2][4] = {};
    for (int k0 = 0; k0 < 768; k0 += 32) {
        __syncthreads();
        gload16(srcA + k0, &As[dA]);
        #pragma unroll
        for (int c = 0; c < 2; c++)
            gload16(srcB[c] + k0, &Bs[dB[c]]);
        __syncthreads();
        bf16x8 av[2], bv[4];
        #pragma unroll
        for (int m = 0; m < 2; m++) av[m] = *(const bf16x8*)&As[aoff[m]];
        #pragma unroll
        for (int n = 0; n < 4; n++) bv[n] = *(const bf16x8*)&Bs[boff[n]];
        #pragma unroll
        for (int m = 0; m < 2; m++)
            #pragma unroll
            for (int n = 0; n < 4; n++)
                acc[m][n] = __builtin_amdgcn_mfma_f32_16x16x32_bf16(av[m], bv[n], acc[m][n], 0, 0, 0);
    }

    float bv4[4];
    #pragma unroll
    for (int n = 0; n < 4; n++) bv4[n] = bp[col0 + wc * 64 + n * 16 + i15];

    #pragma unroll
    for (int m = 0; m < 2; m++) {
        #pragma unroll
        for (int n = 0; n < 4; n++) {
            const int col = col0 + wc * 64 + n * 16 + i15;
            #pragma unroll
            for (int r = 0; r < 4; r++) {
                const int row = row0 + wr * 32 + m * 16 + g * 4 + r;
                long idx = (long)row * 768 + col;
                out[idx] = acc[m][n][r] + bv4[n] + resid[idx];
            }
        }
    }
}

extern "C" void kernel_launch(void* const* d_in, const int* in_sizes, int n_in,
                              void* d_out, int out_size, void* d_ws, size_t ws_size,
                              hipStream_t stream)
{
    const float* x   = (const float*)d_in[0];
    const float* ctx = (const float*)d_in[1];
    const float* Wq  = (const float*)d_in[2];
    const float* bq  = (const float*)d_in[3];
    const float* Wkv = (const float*)d_in[4];
    const float* bkv = (const float*)d_in[5];
    const float* Wp  = (const float*)d_in[6];
    const float* bp  = (const float*)d_in[7];
    const float* g1  = (const float*)d_in[8];
    const float* b1  = (const float*)d_in[9];
    const float* g2  = (const float*)d_in[10];
    const float* b2  = (const float*)d_in[11];
    float* out = (float*)d_out;

    char* w = (char*)d_ws;
    const long SZ_ROWS = 8192L * 768 * 2;   // 12,582,912 B
    long off = 0;
    u16* xn   = (u16*)(w + off); off += SZ_ROWS;
    u16* cn   = (u16*)(w + off); off += SZ_ROWS;
    u16* WqT  = (u16*)(w + off); off += 768L * 768 * 2;
    u16* WkvT = (u16*)(w + off); off += 1536L * 768 * 2;
    u16* WpT  = (u16*)(w + off); off += 768L * 768 * 2;
    u16* Qb   = (u16*)(w + off); off += SZ_ROWS;
    u16* Kb   = (u16*)(w + off); off += SZ_ROWS;
    u16* Vt   = (u16*)(w + off); off += SZ_ROWS;
    u16* Ob   = (u16*)(w + off); off += SZ_ROWS;

    prep_ln_k<<<4672, 256, 0, stream>>>(x, ctx, g1, b1, g2, b2, Wq, Wkv, Wp,
                                        xn, cn, WqT, WkvT, WpT);
    qkv_k<<<1152, 256, 0, stream>>>(xn, cn, WqT, WkvT, bq, bkv, Qb, Kb, Vt);
    flash_k<<<1024, 256, 0, stream>>>(Qb, Kb, Vt, Ob);
    out_k<<<800, 256, 0, stream>>>(Ob, WpT, bp, x, out, out + 6291456L);
}

// Round 18
// 154.284 us; speedup vs baseline: 1.0729x; 1.0729x over previous
//
#include <hip/hip_runtime.h>

typedef unsigned short u16;
typedef short bf16x8 __attribute__((ext_vector_type(8)));
typedef float f32x4 __attribute__((ext_vector_type(4)));
typedef unsigned short u16x8 __attribute__((ext_vector_type(8)));
typedef unsigned short u16x4 __attribute__((ext_vector_type(4)));

union bfr { unsigned int u[4]; bf16x8 v; };

__device__ __forceinline__ u16 f2bf(float f) {
    unsigned int u = __builtin_bit_cast(unsigned int, f);
    u = (u + 0x7fffu + ((u >> 16) & 1u)) >> 16;
    return (u16)u;
}

// v_cvt_pk_bf16_f32: dst = [bf16(hi) : bf16(lo)] (RNE)
__device__ __forceinline__ unsigned int cvtpk(float lo, float hi) {
    unsigned int r;
    asm("v_cvt_pk_bf16_f32 %0, %1, %2" : "=v"(r) : "v"(lo), "v"(hi));
    return r;
}

// async 16B global -> LDS (dest = wave-uniform base + lane*16)
__device__ __forceinline__ void gload16(const u16* src, u16* lds_dst) {
    __builtin_amdgcn_global_load_lds(
        (const __attribute__((address_space(1))) unsigned int*)src,
        (__attribute__((address_space(3))) unsigned int*)lds_dst, 16, 0, 0);
}

// ---------------------------------------------------------------- prep: per-wave LN + tiled transpose
__global__ __launch_bounds__(256) void prep_ln_k(
    const float* __restrict__ x, const float* __restrict__ ctx,
    const float* __restrict__ g1, const float* __restrict__ b1,
    const float* __restrict__ g2, const float* __restrict__ b2,
    const float* __restrict__ Wq, const float* __restrict__ Wkv,
    const float* __restrict__ Wp,
    u16* __restrict__ xn, u16* __restrict__ cn,
    u16* __restrict__ WqT, u16* __restrict__ WkvT, u16* __restrict__ WpT)
{
    const int id = blockIdx.x;
    const int t = threadIdx.x;
    if (id >= 4096) {
        __shared__ float T[64][65];
        int t2 = id - 4096;
        const float* src; u16* dst; int lds, k0, n0;
        if (t2 < 288) { src = Wkv; dst = WkvT; lds = 1536; k0 = (t2 / 24) * 64; n0 = (t2 % 24) * 64; }
        else if (t2 < 432) { int u = t2 - 288; src = Wq; dst = WqT; lds = 768; k0 = (u / 12) * 64; n0 = (u % 12) * 64; }
        else { int u = t2 - 432; src = Wp; dst = WpT; lds = 768; k0 = (u / 12) * 64; n0 = (u % 12) * 64; }
        const int rr = t >> 4, c4 = (t & 15) * 4;
        #pragma unroll
        for (int it = 0; it < 4; it++) {
            int r = rr + it * 16;
            f32x4 v = *(const f32x4*)&src[(long)(k0 + r) * lds + n0 + c4];
            #pragma unroll
            for (int j = 0; j < 4; j++) T[c4 + j][r] = v[j];
        }
        __syncthreads();
        #pragma unroll
        for (int it = 0; it < 4; it++) {
            int r = rr + it * 16;
            u16x4 w;
            #pragma unroll
            for (int j = 0; j < 4; j++) w[j] = f2bf(T[r][c4 + j]);
            *(u16x4*)&dst[(long)(n0 + r) * 768 + k0 + c4] = w;
        }
        return;
    }
    const int lane = t & 63, w = t >> 6;
    const int row = id * 4 + w;
    const float* src; const float* g; const float* b; u16* dst;
    if (row < 8192) { src = x + (long)row * 768; g = g1; b = b1; dst = xn + (long)row * 768; }
    else { int r = row - 8192; src = ctx + (long)r * 768; g = g2; b = b2; dst = cn + (long)r * 768; }

    const int c0 = lane * 4;
    f32x4 v0 = *(const f32x4*)&src[c0];
    f32x4 v1 = *(const f32x4*)&src[c0 + 256];
    f32x4 v2 = *(const f32x4*)&src[c0 + 512];
    float s = (v0[0] + v0[1] + v0[2] + v0[3]) + (v1[0] + v1[1] + v1[2] + v1[3])
            + (v2[0] + v2[1] + v2[2] + v2[3]);
    #pragma unroll
    for (int o = 32; o; o >>= 1) s += __shfl_xor(s, o);
    const float mu = s * (1.0f / 768.0f);
    float q = 0.f;
    #pragma unroll
    for (int j = 0; j < 4; j++) { float d = v0[j] - mu; q += d * d; }
    #pragma unroll
    for (int j = 0; j < 4; j++) { float d = v1[j] - mu; q += d * d; }
    #pragma unroll
    for (int j = 0; j < 4; j++) { float d = v2[j] - mu; q += d * d; }
    #pragma unroll
    for (int o = 32; o; o >>= 1) q += __shfl_xor(q, o);
    const float rs = rsqrtf(q * (1.0f / 768.0f) + 1e-5f);

    f32x4 ga0 = *(const f32x4*)&g[c0],       ba0 = *(const f32x4*)&b[c0];
    f32x4 ga1 = *(const f32x4*)&g[c0 + 256], ba1 = *(const f32x4*)&b[c0 + 256];
    f32x4 ga2 = *(const f32x4*)&g[c0 + 512], ba2 = *(const f32x4*)&b[c0 + 512];
    u16x4 w0, w1, w2;
    #pragma unroll
    for (int j = 0; j < 4; j++) {
        w0[j] = f2bf((v0[j] - mu) * rs * ga0[j] + ba0[j]);
        w1[j] = f2bf((v1[j] - mu) * rs * ga1[j] + ba1[j]);
        w2[j] = f2bf((v2[j] - mu) * rs * ga2[j] + ba2[j]);
    }
    *(u16x4*)&dst[c0]       = w0;
    *(u16x4*)&dst[c0 + 256] = w1;
    *(u16x4*)&dst[c0 + 512] = w2;
}

// ---------------------------------------------------------------- fused Q + KV projection (r12 form, best known)
__global__ __launch_bounds__(256) void qkv_k(
    const u16* __restrict__ xn, const u16* __restrict__ cn,
    const u16* __restrict__ WqT, const u16* __restrict__ WkvT,
    const float* __restrict__ bq, const float* __restrict__ bkv,
    u16* __restrict__ Qb, u16* __restrict__ Kb, u16* __restrict__ Vt)
{
    __shared__ u16 As[128 * 32];
    __shared__ u16 Bs[128 * 32];
    const int id = blockIdx.x;
    const int swz = (id & 7) * 144 + (id >> 3);   // XCD-chunked over 1152
    const int tid = threadIdx.x, lane = tid & 63, wid = tid >> 6;
    const int wr = wid >> 1, wc = wid & 1;
    const int g = lane >> 4, i15 = lane & 15;

    const bool isQ = swz < 384;
    int rt, ct;
    const u16* A; const u16* Bt; const float* bias;
    if (isQ) { rt = swz / 6;  ct = swz % 6;  A = xn; Bt = WqT;  bias = bq; }
    else { int s2 = swz - 384; rt = s2 / 12; ct = s2 % 12; A = cn; Bt = WkvT; bias = bkv; }
    const int row0 = rt * 128, col0 = ct * 128;

    const u16* srcA[2]; const u16* srcB[2]; int ldsOff[2];
    #pragma unroll
    for (int c = 0; c < 2; c++) {
        int P0 = (wid * 2 + c) * 1024;
        int P = P0 + lane * 16;
        int r = P >> 6;
        int slot = (P >> 4) & 3;
        int colx = ((slot ^ ((r >> 1) & 3)) << 3);   // pre-swizzled source col
        srcA[c] = A  + (long)(row0 + r) * 768 + colx;
        srcB[c] = Bt + (long)(col0 + r) * 768 + colx;
        ldsOff[c] = P0 >> 1;
    }

    int aoff[4], boff[4];
    #pragma unroll
    for (int m = 0; m < 4; m++) {
        int R = wr * 64 + m * 16 + i15;
        aoff[m] = R * 32 + ((g ^ ((R >> 1) & 3)) << 3);
    }
    #pragma unroll
    for (int n = 0; n < 4; n++) {
        int R = wc * 64 + n * 16 + i15;
        boff[n] = R * 32 + ((g ^ ((R >> 1) & 3)) << 3);
    }

    f32x4 acc[4][4] = {};
    for (int k0 = 0; k0 < 768; k0 += 32) {
        __syncthreads();
        #pragma unroll
        for (int c = 0; c < 2; c++) {
            gload16(srcA[c] + k0, &As[ldsOff[c]]);
            gload16(srcB[c] + k0, &Bs[ldsOff[c]]);
        }
        __syncthreads();
        bf16x8 av[4], bv[4];
        #pragma unroll
        for (int m = 0; m < 4; m++) av[m] = *(const bf16x8*)&As[aoff[m]];
        #pragma unroll
        for (int n = 0; n < 4; n++) bv[n] = *(const bf16x8*)&Bs[boff[n]];
        #pragma unroll
        for (int m = 0; m < 4; m++)
            #pragma unroll
            for (int n = 0; n < 4; n++)
                acc[m][n] = __builtin_amdgcn_mfma_f32_16x16x32_bf16(av[m], bv[n], acc[m][n], 0, 0, 0);
    }

    float bv4[4];
    #pragma unroll
    for (int n = 0; n < 4; n++) bv4[n] = bias[col0 + wc * 64 + n * 16 + i15];

    #pragma unroll
    for (int m = 0; m < 4; m++) {
        #pragma unroll
        for (int n = 0; n < 4; n++) {
            const int col = col0 + wc * 64 + n * 16 + i15;
            #pragma unroll
            for (int r = 0; r < 4; r++) {
                const int row = row0 + wr * 64 + m * 16 + g * 4 + r;
                float v = acc[m][n][r];
                if (isQ) {
                    v = (v + bv4[n]) * 0.14724444706f;   // 96^-0.5 * log2(e)
                    int b = row >> 10, l = row & 1023;
                    int h = col / 96, d = col % 96;
                    Qb[((long)(b * 8 + h) * 1024 + l) * 96 + d] = f2bf(v);
                } else {
                    v += bv4[n];
                    int b = row >> 10, mt = row & 1023;
                    if (col < 768) {
                        int h = col / 96, d = col % 96;
                        Kb[((long)(b * 8 + h) * 1024 + mt) * 96 + d] = f2bf(v);
                    } else {
                        int cc = col - 768;
                        int h = cc / 96, d = cc % 96;
                        Vt[((long)(b * 8 + h) * 96 + d) * 1024 + mt] = f2bf(v);
                    }
                }
            }
        }
    }
}

// ---------------------------------------------------------------- fused flash attention (r15 form, best known)
__global__ __launch_bounds__(256) void flash_k(
    const u16* __restrict__ Qb, const u16* __restrict__ Kb,
    const u16* __restrict__ Vt, u16* __restrict__ Ob)
{
    const int i = blockIdx.x;
    const int s8 = i >> 3;
    const int bh = (i & 7) * 8 + (s8 >> 4);   // XCD-grouped: 8 bh per XCD
    const int qt = s8 & 15;
    const int tid = threadIdx.x, lane = tid & 63, wid = tid >> 6;
    const int g = lane >> 4, i15 = lane & 15;

    __shared__ u16 Ks[6144];      // single buffer, 12 KB, twisted slots
    __shared__ u16 Vs[2][6144];   // [96][64] swizzled, 2 x 12 KB

    const long baseQK = (long)bh * 98304;
    const u16* Kt  = Kb + baseQK;
    const u16* Vtp = Vt + baseQK;

    bf16x8 qf[3];
    {
        const u16* qrow = Qb + baseQK + (long)(qt * 64 + wid * 16 + i15) * 96 + g * 8;
        qf[0] = *(const bf16x8*)(qrow);
        qf[1] = *(const bf16x8*)(qrow + 32);
        qf[2] = *(const bf16x8*)(qrow + 64);
    }

    int krd[4][3];
    #pragma unroll
    for (int n = 0; n < 4; n++) {
        int q4 = i15 >> 2, rr = i15 & 3, m = n >> 1;
        int R = (n & 1) ? (m * 32 + ((q4 ^ 2) << 3) + 4 + rr)
                        : (m * 32 + (q4 << 3) + rr);
        #pragma unroll
        for (int kd = 0; kd < 3; kd++)
            krd[n][kd] = kd * 2048 + R * 32 + ((g ^ ((R >> 3) & 3) ^ kd) << 3);
    }
    int vrd[6][2];
    #pragma unroll
    for (int n6 = 0; n6 < 6; n6++) {
        int row = n6 * 16 + i15;
        #pragma unroll
        for (int kk = 0; kk < 2; kk++)
            vrd[n6][kk] = row * 64 + ((kk * 32 + g * 8) ^ ((row & 7) << 3));
    }

    int kgo[3], kwr[3], vgo[3], vwr[3];
    #pragma unroll
    for (int it = 0; it < 3; it++) {
        int e = tid + it * 256;
        int r = e / 12, cEl = (e % 12) * 8;
        int kd = cEl >> 5, slot = (cEl >> 3) & 3;
        kgo[it] = r * 96 + cEl;
        kwr[it] = kd * 2048 + r * 32 + ((slot ^ ((r >> 3) & 3) ^ kd) << 3);
        int d = e >> 3, m8 = (e & 7) * 8;
        vgo[it] = d * 1024 + m8;
        vwr[it] = d * 64 + (m8 ^ ((d & 7) << 3));
    }

    u16x8 kreg[3], vreg[3];
    #pragma unroll
    for (int it = 0; it < 3; it++) {
        kreg[it] = *(const u16x8*)&Kt[kgo[it]];
        vreg[it] = *(const u16x8*)&Vtp[vgo[it]];
    }
    #pragma unroll
    for (int it = 0; it < 3; it++) {
        *(u16x8*)&Ks[kwr[it]] = kreg[it];
        *(u16x8*)&Vs[0][vwr[it]] = vreg[it];
    }

    f32x4 o[6] = {};
    float lsum = 0.f;
    int cur = 0;

    for (int t = 0; t < 16; t++) {
        __syncthreads();
        if (t < 15) {
            #pragma unroll
            for (int it = 0; it < 3; it++) {
                kreg[it] = *(const u16x8*)&Kt[(t + 1) * 6144 + kgo[it]];
                vreg[it] = *(const u16x8*)&Vtp[(t + 1) * 64 + vgo[it]];
            }
        }

        f32x4 s[4] = {};
        #pragma unroll
        for (int kd = 0; kd < 3; kd++) {
            #pragma unroll
            for (int n = 0; n < 4; n++) {
                bf16x8 kf = *(const bf16x8*)&Ks[krd[n][kd]];
                s[n] = __builtin_amdgcn_mfma_f32_16x16x32_bf16(kf, qf[kd], s[n], 0, 0, 0);
            }
        }
        __syncthreads();
        if (t < 15) {
            #pragma unroll
            for (int it = 0; it < 3; it++)
                *(u16x8*)&Ks[kwr[it]] = kreg[it];
        }

        unsigned int pk[4][2];
        #pragma unroll
        for (int n = 0; n < 4; n++) {
            float p0 = exp2f(s[n][0]), p1 = exp2f(s[n][1]);
            float p2 = exp2f(s[n][2]), p3 = exp2f(s[n][3]);
            lsum += (p0 + p1) + (p2 + p3);
            pk[n][0] = cvtpk(p0, p1);
            pk[n][1] = cvtpk(p2, p3);
        }

        #pragma unroll
        for (int kk = 0; kk < 2; kk++) {
            bfr pa;
            pa.u[0] = pk[kk * 2][0];
            pa.u[1] = pk[kk * 2][1];
            pa.u[2] = __shfl_xor(pk[kk * 2 + 1][0], 32);
            pa.u[3] = __shfl_xor(pk[kk * 2 + 1][1], 32);
            #pragma unroll
            for (int n6 = 0; n6 < 6; n6++) {
                bf16x8 vf = *(const bf16x8*)&Vs[cur][vrd[n6][kk]];
                o[n6] = __builtin_amdgcn_mfma_f32_16x16x32_bf16(pa.v, vf, o[n6], 0, 0, 0);
            }
        }

        if (t < 15) {
            #pragma unroll
            for (int it = 0; it < 3; it++)
                *(u16x8*)&Vs[cur ^ 1][vwr[it]] = vreg[it];
        }
        cur ^= 1;
    }

    lsum += __shfl_xor(lsum, 16);
    lsum += __shfl_xor(lsum, 32);
    float linv = 1.0f / lsum;

    const int b = bh >> 3, h = bh & 7;
    #pragma unroll
    for (int r = 0; r < 4; r++) {
        float lr = __shfl(linv, g * 4 + r);
        int row = qt * 64 + wid * 16 + g * 4 + r;
        long base = ((long)(b * 1024 + row)) * 768 + h * 96;
        #pragma unroll
        for (int n6 = 0; n6 < 6; n6++)
            Ob[base + n6 * 16 + i15] = f2bf(o[n6][r] * lr);
    }
}

// ---------------------------------------------------------------- out projection + residual + attn_map (r12 form)
__global__ __launch_bounds__(256) void out_k(
    const u16* __restrict__ Ob, const u16* __restrict__ WpT,
    const float* __restrict__ bp, const float* __restrict__ resid,
    float* __restrict__ out, float* __restrict__ amap)
{
    const int id = blockIdx.x;
    if (id >= 384) {
        amap[(id - 384) * 256 + threadIdx.x] = 1.0f;
        return;
    }
    __shared__ u16 As[128 * 32];
    __shared__ u16 Bs[128 * 32];
    const int swz = (id & 7) * 48 + (id >> 3);
    const int rt = swz / 6, ct = swz % 6;
    const int row0 = rt * 128, col0 = ct * 128;
    const int tid = threadIdx.x, lane = tid & 63, wid = tid >> 6;
    const int wr = wid >> 1, wc = wid & 1;
    const int g = lane >> 4, i15 = lane & 15;

    const u16* srcA[2]; const u16* srcB[2]; int ldsOff[2];
    #pragma unroll
    for (int c = 0; c < 2; c++) {
        int P0 = (wid * 2 + c) * 1024;
        int P = P0 + lane * 16;
        int r = P >> 6;
        int slot = (P >> 4) & 3;
        int colx = ((slot ^ ((r >> 1) & 3)) << 3);
        srcA[c] = Ob  + (long)(row0 + r) * 768 + colx;
        srcB[c] = WpT + (long)(col0 + r) * 768 + colx;
        ldsOff[c] = P0 >> 1;
    }

    int aoff[4], boff[4];
    #pragma unroll
    for (int m = 0; m < 4; m++) {
        int R = wr * 64 + m * 16 + i15;
        aoff[m] = R * 32 + ((g ^ ((R >> 1) & 3)) << 3);
    }
    #pragma unroll
    for (int n = 0; n < 4; n++) {
        int R = wc * 64 + n * 16 + i15;
        boff[n] = R * 32 + ((g ^ ((R >> 1) & 3)) << 3);
    }

    f32x4 acc[4][4] = {};
    for (int k0 = 0; k0 < 768; k0 += 32) {
        __syncthreads();
        #pragma unroll
        for (int c = 0; c < 2; c++) {
            gload16(srcA[c] + k0, &As[ldsOff[c]]);
            gload16(srcB[c] + k0, &Bs[ldsOff[c]]);
        }
        __syncthreads();
        bf16x8 av[4], bv[4];
        #pragma unroll
        for (int m = 0; m < 4; m++) av[m] = *(const bf16x8*)&As[aoff[m]];
        #pragma unroll
        for (int n = 0; n < 4; n++) bv[n] = *(const bf16x8*)&Bs[boff[n]];
        #pragma unroll
        for (int m = 0; m < 4; m++)
            #pragma unroll
            for (int n = 0; n < 4; n++)
                acc[m][n] = __builtin_amdgcn_mfma_f32_16x16x32_bf16(av[m], bv[n], acc[m][n], 0, 0, 0);
    }

    float bv4[4];
    #pragma unroll
    for (int n = 0; n < 4; n++) bv4[n] = bp[col0 + wc * 64 + n * 16 + i15];

    #pragma unroll
    for (int m = 0; m < 4; m++) {
        #pragma unroll
        for (int n = 0; n < 4; n++) {
            const int col = col0 + wc * 64 + n * 16 + i15;
            #pragma unroll
            for (int r = 0; r < 4; r++) {
                const int row = row0 + wr * 64 + m * 16 + g * 4 + r;
                long idx = (long)row * 768 + col;
                out[idx] = acc[m][n][r] + bv4[n] + resid[idx];
            }
        }
    }
}

extern "C" void kernel_launch(void* const* d_in, const int* in_sizes, int n_in,
                              void* d_out, int out_size, void* d_ws, size_t ws_size,
                              hipStream_t stream)
{
    const float* x   = (const float*)d_in[0];
    const float* ctx = (const float*)d_in[1];
    const float* Wq  = (const float*)d_in[2];
    const float* bq  = (const float*)d_in[3];
    const float* Wkv = (const float*)d_in[4];
    const float* bkv = (const float*)d_in[5];
    const float* Wp  = (const float*)d_in[6];
    const float* bp  = (const float*)d_in[7];
    const float* g1  = (const float*)d_in[8];
    const float* b1  = (const float*)d_in[9];
    const float* g2  = (const float*)d_in[10];
    const float* b2  = (const float*)d_in[11];
    float* out = (float*)d_out;

    char* w = (char*)d_ws;
    const long SZ_ROWS = 8192L * 768 * 2;   // 12,582,912 B
    long off = 0;
    u16* xn   = (u16*)(w + off); off += SZ_ROWS;
    u16* cn   = (u16*)(w + off); off += SZ_ROWS;
    u16* WqT  = (u16*)(w + off); off += 768L * 768 * 2;
    u16* WkvT = (u16*)(w + off); off += 1536L * 768 * 2;
    u16* WpT  = (u16*)(w + off); off += 768L * 768 * 2;
    u16* Qb   = (u16*)(w + off); off += SZ_ROWS;
    u16* Kb   = (u16*)(w + off); off += SZ_ROWS;
    u16* Vt   = (u16*)(w + off); off += SZ_ROWS;
    u16* Ob   = (u16*)(w + off); off += SZ_ROWS;

    prep_ln_k<<<4672, 256, 0, stream>>>(x, ctx, g1, b1, g2, b2, Wq, Wkv, Wp,
                                        xn, cn, WqT, WkvT, WpT);
    qkv_k<<<1152, 256, 0, stream>>>(xn, cn, WqT, WkvT, bq, bkv, Qb, Kb, Vt);
    flash_k<<<1024, 256, 0, stream>>>(Qb, Kb, Vt, Ob);
    out_k<<<416, 256, 0, stream>>>(Ob, WpT, bp, x, out, out + 6291456L);
}

// Round 19
// 152.003 us; speedup vs baseline: 1.0890x; 1.0150x over previous
//
#include <hip/hip_runtime.h>

typedef unsigned short u16;
typedef short bf16x8 __attribute__((ext_vector_type(8)));
typedef float f32x4 __attribute__((ext_vector_type(4)));
typedef unsigned short u16x8 __attribute__((ext_vector_type(8)));
typedef unsigned short u16x4 __attribute__((ext_vector_type(4)));

union bfr { unsigned int u[4]; bf16x8 v; };

__device__ __forceinline__ u16 f2bf(float f) {
    unsigned int u = __builtin_bit_cast(unsigned int, f);
    u = (u + 0x7fffu + ((u >> 16) & 1u)) >> 16;
    return (u16)u;
}

// v_cvt_pk_bf16_f32: dst = [bf16(hi) : bf16(lo)] (RNE)
__device__ __forceinline__ unsigned int cvtpk(float lo, float hi) {
    unsigned int r;
    asm("v_cvt_pk_bf16_f32 %0, %1, %2" : "=v"(r) : "v"(lo), "v"(hi));
    return r;
}

// async 16B global -> LDS (dest = wave-uniform base + lane*16)
__device__ __forceinline__ void gload16(const u16* src, u16* lds_dst) {
    __builtin_amdgcn_global_load_lds(
        (const __attribute__((address_space(1))) unsigned int*)src,
        (__attribute__((address_space(3))) unsigned int*)lds_dst, 16, 0, 0);
}

// ---------------------------------------------------------------- prep: per-wave LN + tiled transpose + amap fill
// id < 4096: LN (4 rows/block, wave-per-row). 4096..4671: weight transpose.
// id >= 4672: attn_map = 1.0 (analytic; no dependency on anything).
__global__ __launch_bounds__(256) void prep_ln_k(
    const float* __restrict__ x, const float* __restrict__ ctx,
    const float* __restrict__ g1, const float* __restrict__ b1,
    const float* __restrict__ g2, const float* __restrict__ b2,
    const float* __restrict__ Wq, const float* __restrict__ Wkv,
    const float* __restrict__ Wp,
    u16* __restrict__ xn, u16* __restrict__ cn,
    u16* __restrict__ WqT, u16* __restrict__ WkvT, u16* __restrict__ WpT,
    float* __restrict__ amap)
{
    const int id = blockIdx.x;
    const int t = threadIdx.x;
    if (id >= 4672) {                         // attn_map == 1.0 analytically
        amap[(id - 4672) * 256 + t] = 1.0f;
        return;
    }
    if (id >= 4096) {
        __shared__ float T[64][65];
        int t2 = id - 4096;
        const float* src; u16* dst; int lds, k0, n0;
        if (t2 < 288) { src = Wkv; dst = WkvT; lds = 1536; k0 = (t2 / 24) * 64; n0 = (t2 % 24) * 64; }
        else if (t2 < 432) { int u = t2 - 288; src = Wq; dst = WqT; lds = 768; k0 = (u / 12) * 64; n0 = (u % 12) * 64; }
        else { int u = t2 - 432; src = Wp; dst = WpT; lds = 768; k0 = (u / 12) * 64; n0 = (u % 12) * 64; }
        const int rr = t >> 4, c4 = (t & 15) * 4;
        #pragma unroll
        for (int it = 0; it < 4; it++) {
            int r = rr + it * 16;
            f32x4 v = *(const f32x4*)&src[(long)(k0 + r) * lds + n0 + c4];
            #pragma unroll
            for (int j = 0; j < 4; j++) T[c4 + j][r] = v[j];
        }
        __syncthreads();
        #pragma unroll
        for (int it = 0; it < 4; it++) {
            int r = rr + it * 16;
            u16x4 w;
            #pragma unroll
            for (int j = 0; j < 4; j++) w[j] = f2bf(T[r][c4 + j]);
            *(u16x4*)&dst[(long)(n0 + r) * 768 + k0 + c4] = w;
        }
        return;
    }
    const int lane = t & 63, w = t >> 6;
    const int row = id * 4 + w;
    const float* src; const float* g; const float* b; u16* dst;
    if (row < 8192) { src = x + (long)row * 768; g = g1; b = b1; dst = xn + (long)row * 768; }
    else { int r = row - 8192; src = ctx + (long)r * 768; g = g2; b = b2; dst = cn + (long)r * 768; }

    const int c0 = lane * 4;
    f32x4 v0 = *(const f32x4*)&src[c0];
    f32x4 v1 = *(const f32x4*)&src[c0 + 256];
    f32x4 v2 = *(const f32x4*)&src[c0 + 512];
    float s = (v0[0] + v0[1] + v0[2] + v0[3]) + (v1[0] + v1[1] + v1[2] + v1[3])
            + (v2[0] + v2[1] + v2[2] + v2[3]);
    #pragma unroll
    for (int o = 32; o; o >>= 1) s += __shfl_xor(s, o);
    const float mu = s * (1.0f / 768.0f);
    float q = 0.f;
    #pragma unroll
    for (int j = 0; j < 4; j++) { float d = v0[j] - mu; q += d * d; }
    #pragma unroll
    for (int j = 0; j < 4; j++) { float d = v1[j] - mu; q += d * d; }
    #pragma unroll
    for (int j = 0; j < 4; j++) { float d = v2[j] - mu; q += d * d; }
    #pragma unroll
    for (int o = 32; o; o >>= 1) q += __shfl_xor(q, o);
    const float rs = rsqrtf(q * (1.0f / 768.0f) + 1e-5f);

    f32x4 ga0 = *(const f32x4*)&g[c0],       ba0 = *(const f32x4*)&b[c0];
    f32x4 ga1 = *(const f32x4*)&g[c0 + 256], ba1 = *(const f32x4*)&b[c0 + 256];
    f32x4 ga2 = *(const f32x4*)&g[c0 + 512], ba2 = *(const f32x4*)&b[c0 + 512];
    u16x4 w0, w1, w2;
    #pragma unroll
    for (int j = 0; j < 4; j++) {
        w0[j] = f2bf((v0[j] - mu) * rs * ga0[j] + ba0[j]);
        w1[j] = f2bf((v1[j] - mu) * rs * ga1[j] + ba1[j]);
        w2[j] = f2bf((v2[j] - mu) * rs * ga2[j] + ba2[j]);
    }
    *(u16x4*)&dst[c0]       = w0;
    *(u16x4*)&dst[c0 + 256] = w1;
    *(u16x4*)&dst[c0 + 512] = w2;
}

// ---------------------------------------------------------------- fused Q + KV projection (r12 form, best known)
__global__ __launch_bounds__(256) void qkv_k(
    const u16* __restrict__ xn, const u16* __restrict__ cn,
    const u16* __restrict__ WqT, const u16* __restrict__ WkvT,
    const float* __restrict__ bq, const float* __restrict__ bkv,
    u16* __restrict__ Qb, u16* __restrict__ Kb, u16* __restrict__ Vt)
{
    __shared__ u16 As[128 * 32];
    __shared__ u16 Bs[128 * 32];
    const int id = blockIdx.x;
    const int swz = (id & 7) * 144 + (id >> 3);   // XCD-chunked over 1152
    const int tid = threadIdx.x, lane = tid & 63, wid = tid >> 6;
    const int wr = wid >> 1, wc = wid & 1;
    const int g = lane >> 4, i15 = lane & 15;

    const bool isQ = swz < 384;
    int rt, ct;
    const u16* A; const u16* Bt; const float* bias;
    if (isQ) { rt = swz / 6;  ct = swz % 6;  A = xn; Bt = WqT;  bias = bq; }
    else { int s2 = swz - 384; rt = s2 / 12; ct = s2 % 12; A = cn; Bt = WkvT; bias = bkv; }
    const int row0 = rt * 128, col0 = ct * 128;

    const u16* srcA[2]; const u16* srcB[2]; int ldsOff[2];
    #pragma unroll
    for (int c = 0; c < 2; c++) {
        int P0 = (wid * 2 + c) * 1024;
        int P = P0 + lane * 16;
        int r = P >> 6;
        int slot = (P >> 4) & 3;
        int colx = ((slot ^ ((r >> 1) & 3)) << 3);   // pre-swizzled source col
        srcA[c] = A  + (long)(row0 + r) * 768 + colx;
        srcB[c] = Bt + (long)(col0 + r) * 768 + colx;
        ldsOff[c] = P0 >> 1;
    }

    int aoff[4], boff[4];
    #pragma unroll
    for (int m = 0; m < 4; m++) {
        int R = wr * 64 + m * 16 + i15;
        aoff[m] = R * 32 + ((g ^ ((R >> 1) & 3)) << 3);
    }
    #pragma unroll
    for (int n = 0; n < 4; n++) {
        int R = wc * 64 + n * 16 + i15;
        boff[n] = R * 32 + ((g ^ ((R >> 1) & 3)) << 3);
    }

    f32x4 acc[4][4] = {};
    for (int k0 = 0; k0 < 768; k0 += 32) {
        __syncthreads();
        #pragma unroll
        for (int c = 0; c < 2; c++) {
            gload16(srcA[c] + k0, &As[ldsOff[c]]);
            gload16(srcB[c] + k0, &Bs[ldsOff[c]]);
        }
        __syncthreads();
        bf16x8 av[4], bv[4];
        #pragma unroll
        for (int m = 0; m < 4; m++) av[m] = *(const bf16x8*)&As[aoff[m]];
        #pragma unroll
        for (int n = 0; n < 4; n++) bv[n] = *(const bf16x8*)&Bs[boff[n]];
        #pragma unroll
        for (int m = 0; m < 4; m++)
            #pragma unroll
            for (int n = 0; n < 4; n++)
                acc[m][n] = __builtin_amdgcn_mfma_f32_16x16x32_bf16(av[m], bv[n], acc[m][n], 0, 0, 0);
    }

    float bv4[4];
    #pragma unroll
    for (int n = 0; n < 4; n++) bv4[n] = bias[col0 + wc * 64 + n * 16 + i15];

    #pragma unroll
    for (int m = 0; m < 4; m++) {
        #pragma unroll
        for (int n = 0; n < 4; n++) {
            const int col = col0 + wc * 64 + n * 16 + i15;
            #pragma unroll
            for (int r = 0; r < 4; r++) {
                const int row = row0 + wr * 64 + m * 16 + g * 4 + r;
                float v = acc[m][n][r];
                if (isQ) {
                    v = (v + bv4[n]) * 0.14724444706f;   // 96^-0.5 * log2(e)
                    int b = row >> 10, l = row & 1023;
                    int h = col / 96, d = col % 96;
                    Qb[((long)(b * 8 + h) * 1024 + l) * 96 + d] = f2bf(v);
                } else {
                    v += bv4[n];
                    int b = row >> 10, mt = row & 1023;
                    if (col < 768) {
                        int h = col / 96, d = col % 96;
                        Kb[((long)(b * 8 + h) * 1024 + mt) * 96 + d] = f2bf(v);
                    } else {
                        int cc = col - 768;
                        int h = cc / 96, d = cc % 96;
                        Vt[((long)(b * 8 + h) * 96 + d) * 1024 + mt] = f2bf(v);
                    }
                }
            }
        }
    }
}

// ---------------------------------------------------------------- fused flash attention (r15 form + T5 setprio)
__global__ __launch_bounds__(256) void flash_k(
    const u16* __restrict__ Qb, const u16* __restrict__ Kb,
    const u16* __restrict__ Vt, u16* __restrict__ Ob)
{
    const int i = blockIdx.x;
    const int s8 = i >> 3;
    const int bh = (i & 7) * 8 + (s8 >> 4);   // XCD-grouped: 8 bh per XCD
    const int qt = s8 & 15;
    const int tid = threadIdx.x, lane = tid & 63, wid = tid >> 6;
    const int g = lane >> 4, i15 = lane & 15;

    __shared__ u16 Ks[6144];      // single buffer, 12 KB, twisted slots
    __shared__ u16 Vs[2][6144];   // [96][64] swizzled, 2 x 12 KB

    const long baseQK = (long)bh * 98304;
    const u16* Kt  = Kb + baseQK;
    const u16* Vtp = Vt + baseQK;

    bf16x8 qf[3];
    {
        const u16* qrow = Qb + baseQK + (long)(qt * 64 + wid * 16 + i15) * 96 + g * 8;
        qf[0] = *(const bf16x8*)(qrow);
        qf[1] = *(const bf16x8*)(qrow + 32);
        qf[2] = *(const bf16x8*)(qrow + 64);
    }

    int krd[4][3];
    #pragma unroll
    for (int n = 0; n < 4; n++) {
        int q4 = i15 >> 2, rr = i15 & 3, m = n >> 1;
        int R = (n & 1) ? (m * 32 + ((q4 ^ 2) << 3) + 4 + rr)
                        : (m * 32 + (q4 << 3) + rr);
        #pragma unroll
        for (int kd = 0; kd < 3; kd++)
            krd[n][kd] = kd * 2048 + R * 32 + ((g ^ ((R >> 3) & 3) ^ kd) << 3);
    }
    int vrd[6][2];
    #pragma unroll
    for (int n6 = 0; n6 < 6; n6++) {
        int row = n6 * 16 + i15;
        #pragma unroll
        for (int kk = 0; kk < 2; kk++)
            vrd[n6][kk] = row * 64 + ((kk * 32 + g * 8) ^ ((row & 7) << 3));
    }

    int kgo[3], kwr[3], vgo[3], vwr[3];
    #pragma unroll
    for (int it = 0; it < 3; it++) {
        int e = tid + it * 256;
        int r = e / 12, cEl = (e % 12) * 8;
        int kd = cEl >> 5, slot = (cEl >> 3) & 3;
        kgo[it] = r * 96 + cEl;
        kwr[it] = kd * 2048 + r * 32 + ((slot ^ ((r >> 3) & 3) ^ kd) << 3);
        int d = e >> 3, m8 = (e & 7) * 8;
        vgo[it] = d * 1024 + m8;
        vwr[it] = d * 64 + (m8 ^ ((d & 7) << 3));
    }

    u16x8 kreg[3], vreg[3];
    #pragma unroll
    for (int it = 0; it < 3; it++) {
        kreg[it] = *(const u16x8*)&Kt[kgo[it]];
        vreg[it] = *(const u16x8*)&Vtp[vgo[it]];
    }
    #pragma unroll
    for (int it = 0; it < 3; it++) {
        *(u16x8*)&Ks[kwr[it]] = kreg[it];
        *(u16x8*)&Vs[0][vwr[it]] = vreg[it];
    }

    f32x4 o[6] = {};
    float lsum = 0.f;
    int cur = 0;

    for (int t = 0; t < 16; t++) {
        __syncthreads();
        if (t < 15) {
            #pragma unroll
            for (int it = 0; it < 3; it++) {
                kreg[it] = *(const u16x8*)&Kt[(t + 1) * 6144 + kgo[it]];
                vreg[it] = *(const u16x8*)&Vtp[(t + 1) * 64 + vgo[it]];
            }
        }

        f32x4 s[4] = {};
        __builtin_amdgcn_s_setprio(1);
        #pragma unroll
        for (int kd = 0; kd < 3; kd++) {
            #pragma unroll
            for (int n = 0; n < 4; n++) {
                bf16x8 kf = *(const bf16x8*)&Ks[krd[n][kd]];
                s[n] = __builtin_amdgcn_mfma_f32_16x16x32_bf16(kf, qf[kd], s[n], 0, 0, 0);
            }
        }
        __builtin_amdgcn_s_setprio(0);
        __syncthreads();
        if (t < 15) {
            #pragma unroll
            for (int it = 0; it < 3; it++)
                *(u16x8*)&Ks[kwr[it]] = kreg[it];
        }

        unsigned int pk[4][2];
        #pragma unroll
        for (int n = 0; n < 4; n++) {
            float p0 = exp2f(s[n][0]), p1 = exp2f(s[n][1]);
            float p2 = exp2f(s[n][2]), p3 = exp2f(s[n][3]);
            lsum += (p0 + p1) + (p2 + p3);
            pk[n][0] = cvtpk(p0, p1);
            pk[n][1] = cvtpk(p2, p3);
        }

        __builtin_amdgcn_s_setprio(1);
        #pragma unroll
        for (int kk = 0; kk < 2; kk++) {
            bfr pa;
            pa.u[0] = pk[kk * 2][0];
            pa.u[1] = pk[kk * 2][1];
            pa.u[2] = __shfl_xor(pk[kk * 2 + 1][0], 32);
            pa.u[3] = __shfl_xor(pk[kk * 2 + 1][1], 32);
            #pragma unroll
            for (int n6 = 0; n6 < 6; n6++) {
                bf16x8 vf = *(const bf16x8*)&Vs[cur][vrd[n6][kk]];
                o[n6] = __builtin_amdgcn_mfma_f32_16x16x32_bf16(pa.v, vf, o[n6], 0, 0, 0);
            }
        }
        __builtin_amdgcn_s_setprio(0);

        if (t < 15) {
            #pragma unroll
            for (int it = 0; it < 3; it++)
                *(u16x8*)&Vs[cur ^ 1][vwr[it]] = vreg[it];
        }
        cur ^= 1;
    }

    lsum += __shfl_xor(lsum, 16);
    lsum += __shfl_xor(lsum, 32);
    float linv = 1.0f / lsum;

    const int b = bh >> 3, h = bh & 7;
    #pragma unroll
    for (int r = 0; r < 4; r++) {
        float lr = __shfl(linv, g * 4 + r);
        int row = qt * 64 + wid * 16 + g * 4 + r;
        long base = ((long)(b * 1024 + row)) * 768 + h * 96;
        #pragma unroll
        for (int n6 = 0; n6 < 6; n6++)
            Ob[base + n6 * 16 + i15] = f2bf(o[n6][r] * lr);
    }
}

// ---------------------------------------------------------------- out projection + residual (r12 form, grid=384)
__global__ __launch_bounds__(256) void out_k(
    const u16* __restrict__ Ob, const u16* __restrict__ WpT,
    const float* __restrict__ bp, const float* __restrict__ resid,
    float* __restrict__ out)
{
    const int id = blockIdx.x;
    __shared__ u16 As[128 * 32];
    __shared__ u16 Bs[128 * 32];
    const int swz = (id & 7) * 48 + (id >> 3);
    const int rt = swz / 6, ct = swz % 6;
    const int row0 = rt * 128, col0 = ct * 128;
    const int tid = threadIdx.x, lane = tid & 63, wid = tid >> 6;
    const int wr = wid >> 1, wc = wid & 1;
    const int g = lane >> 4, i15 = lane & 15;

    const u16* srcA[2]; const u16* srcB[2]; int ldsOff[2];
    #pragma unroll
    for (int c = 0; c < 2; c++) {
        int P0 = (wid * 2 + c) * 1024;
        int P = P0 + lane * 16;
        int r = P >> 6;
        int slot = (P >> 4) & 3;
        int colx = ((slot ^ ((r >> 1) & 3)) << 3);
        srcA[c] = Ob  + (long)(row0 + r) * 768 + colx;
        srcB[c] = WpT + (long)(col0 + r) * 768 + colx;
        ldsOff[c] = P0 >> 1;
    }

    int aoff[4], boff[4];
    #pragma unroll
    for (int m = 0; m < 4; m++) {
        int R = wr * 64 + m * 16 + i15;
        aoff[m] = R * 32 + ((g ^ ((R >> 1) & 3)) << 3);
    }
    #pragma unroll
    for (int n = 0; n < 4; n++) {
        int R = wc * 64 + n * 16 + i15;
        boff[n] = R * 32 + ((g ^ ((R >> 1) & 3)) << 3);
    }

    f32x4 acc[4][4] = {};
    for (int k0 = 0; k0 < 768; k0 += 32) {
        __syncthreads();
        #pragma unroll
        for (int c = 0; c < 2; c++) {
            gload16(srcA[c] + k0, &As[ldsOff[c]]);
            gload16(srcB[c] + k0, &Bs[ldsOff[c]]);
        }
        __syncthreads();
        bf16x8 av[4], bv[4];
        #pragma unroll
        for (int m = 0; m < 4; m++) av[m] = *(const bf16x8*)&As[aoff[m]];
        #pragma unroll
        for (int n = 0; n < 4; n++) bv[n] = *(const bf16x8*)&Bs[boff[n]];
        #pragma unroll
        for (int m = 0; m < 4; m++)
            #pragma unroll
            for (int n = 0; n < 4; n++)
                acc[m][n] = __builtin_amdgcn_mfma_f32_16x16x32_bf16(av[m], bv[n], acc[m][n], 0, 0, 0);
    }

    float bv4[4];
    #pragma unroll
    for (int n = 0; n < 4; n++) bv4[n] = bp[col0 + wc * 64 + n * 16 + i15];

    #pragma unroll
    for (int m = 0; m < 4; m++) {
        #pragma unroll
        for (int n = 0; n < 4; n++) {
            const int col = col0 + wc * 64 + n * 16 + i15;
            #pragma unroll
            for (int r = 0; r < 4; r++) {
                const int row = row0 + wr * 64 + m * 16 + g * 4 + r;
                long idx = (long)row * 768 + col;
                out[idx] = acc[m][n][r] + bv4[n] + resid[idx];
            }
        }
    }
}

extern "C" void kernel_launch(void* const* d_in, const int* in_sizes, int n_in,
                              void* d_out, int out_size, void* d_ws, size_t ws_size,
                              hipStream_t stream)
{
    const float* x   = (const float*)d_in[0];
    const float* ctx = (const float*)d_in[1];
    const float* Wq  = (const float*)d_in[2];
    const float* bq  = (const float*)d_in[3];
    const float* Wkv = (const float*)d_in[4];
    const float* bkv = (const float*)d_in[5];
    const float* Wp  = (const float*)d_in[6];
    const float* bp  = (const float*)d_in[7];
    const float* g1  = (const float*)d_in[8];
    const float* b1  = (const float*)d_in[9];
    const float* g2  = (const float*)d_in[10];
    const float* b2  = (const float*)d_in[11];
    float* out = (float*)d_out;

    char* w = (char*)d_ws;
    const long SZ_ROWS = 8192L * 768 * 2;   // 12,582,912 B
    long off = 0;
    u16* xn   = (u16*)(w + off); off += SZ_ROWS;
    u16* cn   = (u16*)(w + off); off += SZ_ROWS;
    u16* WqT  = (u16*)(w + off); off += 768L * 768 * 2;
    u16* WkvT = (u16*)(w + off); off += 1536L * 768 * 2;
    u16* WpT  = (u16*)(w + off); off += 768L * 768 * 2;
    u16* Qb   = (u16*)(w + off); off += SZ_ROWS;
    u16* Kb   = (u16*)(w + off); off += SZ_ROWS;
    u16* Vt   = (u16*)(w + off); off += SZ_ROWS;
    u16* Ob   = (u16*)(w + off); off += SZ_ROWS;

    prep_ln_k<<<4704, 256, 0, stream>>>(x, ctx, g1, b1, g2, b2, Wq, Wkv, Wp,
                                        xn, cn, WqT, WkvT, WpT, out + 6291456L);
    qkv_k<<<1152, 256, 0, stream>>>(xn, cn, WqT, WkvT, bq, bkv, Qb, Kb, Vt);
    flash_k<<<1024, 256, 0, stream>>>(Qb, Kb, Vt, Ob);
    out_k<<<384, 256, 0, stream>>>(Ob, WpT, bp, x, out);
}